// Round 17
// baseline (3341.940 us; speedup 1.0000x reference)
//
#include <hip/hip_runtime.h>
#include <math.h>

// ---------- types / helpers ----------
typedef __attribute__((ext_vector_type(8))) short bf16x8;   // 8 bf16 = 4 VGPR
typedef __attribute__((ext_vector_type(4))) int   i32x4;
typedef __attribute__((ext_vector_type(4))) float f32x4;    // MFMA acc
typedef __attribute__((ext_vector_type(4))) unsigned short u16x4;

__device__ __forceinline__ unsigned short f2bf(float x) {   // round-to-nearest-even
  unsigned int u = __builtin_bit_cast(unsigned int, x);
  return (unsigned short)((u + 0x7fffu + ((u >> 16) & 1u)) >> 16);
}
__device__ __forceinline__ float bf2f(unsigned short h) {
  unsigned int u = ((unsigned int)h) << 16;
  return __builtin_bit_cast(float, u);
}
// tanh via hw exp2: tanh(z) = 1 - 2/(e^{2z}+1)
__device__ __forceinline__ float fast_tanh(float z) {
  float e;
  asm("v_exp_f32 %0, %1" : "=v"(e) : "v"(z * 2.8853900817779268f));
  return 1.0f - 2.0f * __builtin_amdgcn_rcpf(e + 1.0f);
}

// ---------- K0: convert weights + h0 to bf16; zero flags + xready ----------
__global__ void convert_kernel(const float* __restrict__ w_i2h,
                               const float* __restrict__ w_h2o,
                               const float* __restrict__ h0,
                               unsigned short* __restrict__ wx,
                               unsigned short* __restrict__ wh,
                               unsigned short* __restrict__ w2o,
                               unsigned short* __restrict__ hx,
                               int* __restrict__ flags) {
  int idx = blockIdx.x * 256 + threadIdx.x;
  if (idx < 4352) flags[idx] = 0;          // 4096 padded flags + 256 xready
  int e = idx * 4;
  const float* src;
  unsigned short* dst;
  if (e < 2097152) {                       // w_i2h
    int row = e >> 11, col = e & 2047;
    src = w_i2h + e;
    dst = (col < 1024) ? (wx + row * 1024 + col) : (wh + row * 1024 + (col - 1024));
  } else if (e < 3145728) {                // w_h2o
    int i = e - 2097152; src = w_h2o + i; dst = w2o + i;
  } else {                                 // h0 -> hx slice 0
    int i = e - 3145728; src = h0 + i; dst = hx + i;
  }
  float4 v = *(const float4*)src;
  u16x4 o = {f2bf(v.x), f2bf(v.y), f2bf(v.z), f2bf(v.w)};
  *(u16x4*)dst = o;
}

// ---------- K1: FUSED xproj workers + persistent scan, capacity-proven ----------
// 512 blocks x 256 threads, __launch_bounds__(256,2): VGPR capped at 256 ->
// 2 blocks/CU -> ALL 512 blocks resident by construction (deadlock-free for
// any dispatch order; worst case degenerates to the serial schedule).
//   blockIdx < 256 : scan role (R13 structure, wave 0 only; xp reads sc0sc1;
//                    xready gate confirmed in dwordx4 quads, amortized).
//   blockIdx >= 256: worker w=blockIdx-256 computes 8 xproj tiles
//                    (bx=w&7, by=(w>>3)+32*i) -> by 0..31 complete first.
//                    Per tile: sc0sc1 stores, drain, __syncthreads, one
//                    device-scope atomicAdd(xready[by]).
#define TOTAL_BLOCKS 512
__global__ __launch_bounds__(256, 2) void fused_kernel(const float* __restrict__ x,
                                                       const float* __restrict__ b_i2h,
                                                       const unsigned short* __restrict__ wx,
                                                       const unsigned short* __restrict__ wh,
                                                       const unsigned short* __restrict__ w2o,
                                                       const float* __restrict__ b_h2o,
                                                       unsigned short* __restrict__ xproj,
                                                       float* __restrict__ y,
                                                       unsigned short* __restrict__ hx,
                                                       int* __restrict__ flags,
                                                       int* __restrict__ xready) {
  __shared__ __attribute__((aligned(16))) unsigned short lA[128 * 64];
  __shared__ __attribute__((aligned(16))) unsigned short lB[128 * 64];

  if (blockIdx.x >= 256) {
    // =================== xproj worker role ===================
    const int wkr = blockIdx.x - 256;      // 0..255
    const int bx = wkr & 7, byg = wkr >> 3;
    const int tid = threadIdx.x;
    const int lane = tid & 63, w = tid >> 6;
    const int g = lane >> 4, l15 = lane & 15;
    const int wm = w >> 1, wn = w & 1;
    const int K = 1024;

    for (int i = 0; i < 8; ++i) {
      const int by = byg + 32 * i;
      f32x4 acc[4][4];
#pragma unroll
      for (int a = 0; a < 4; ++a)
#pragma unroll
        for (int c = 0; c < 4; ++c) acc[a][c] = (f32x4){0.f, 0.f, 0.f, 0.f};

      for (int kt = 0; kt < 16; ++kt) {
        const int k0 = kt << 6;
#pragma unroll
        for (int s = 0; s < 4; ++s) {
          int cl = s * 256 + tid;
          int row = cl >> 3, cc = cl & 7;
          const float* ap = x + (size_t)(by * 128 + row) * K + k0 + cc * 8;
          float4 f0 = *(const float4*)ap;
          float4 f1 = *(const float4*)(ap + 4);
          bf16x8 av = (bf16x8){(short)f2bf(f0.x), (short)f2bf(f0.y), (short)f2bf(f0.z), (short)f2bf(f0.w),
                               (short)f2bf(f1.x), (short)f2bf(f1.y), (short)f2bf(f1.z), (short)f2bf(f1.w)};
          *(bf16x8*)&lA[(row * 8 + (cc ^ (row & 7))) * 8] = av;
          const unsigned short* bp = wx + (size_t)(bx * 128 + row) * K + k0 + cc * 8;
          bf16x8 bv = *(const bf16x8*)bp;
          *(bf16x8*)&lB[(row * 8 + (cc ^ (row & 7))) * 8] = bv;
        }
        __syncthreads();
#pragma unroll
        for (int kk = 0; kk < 2; ++kk) {
          bf16x8 av[4], bv[4];
#pragma unroll
          for (int mt = 0; mt < 4; ++mt) {
            int r = wm * 64 + mt * 16 + l15;
            av[mt] = *(const bf16x8*)&lA[(r * 8 + ((kk * 4 + g) ^ (r & 7))) * 8];
          }
#pragma unroll
          for (int nt = 0; nt < 4; ++nt) {
            int r = wn * 64 + nt * 16 + l15;
            bv[nt] = *(const bf16x8*)&lB[(r * 8 + ((kk * 4 + g) ^ (r & 7))) * 8];
          }
#pragma unroll
          for (int mt = 0; mt < 4; ++mt)
#pragma unroll
            for (int nt = 0; nt < 4; ++nt)
              acc[mt][nt] = __builtin_amdgcn_mfma_f32_16x16x32_bf16(av[mt], bv[nt], acc[mt][nt], 0, 0, 0);
        }
        __syncthreads();
      }
      // epilogue: sc0sc1 bf16 stores (L3-visible intra-kernel)
#pragma unroll
      for (int mt = 0; mt < 4; ++mt) {
        int grow = by * 128 + wm * 64 + mt * 16 + g * 4;
#pragma unroll
        for (int nt = 0; nt < 4; ++nt) {
          int col = bx * 128 + wn * 64 + nt * 16 + l15;
          float bs = b_i2h[col];
#pragma unroll
          for (int r = 0; r < 4; ++r) {
            unsigned int hv = f2bf(acc[mt][nt][r] + bs);
            const unsigned short* p = xproj + (size_t)(grow + r) * 1024 + col;
            asm volatile("global_store_short %0, %1, off sc0 sc1"
                         :: "v"(p), "v"(hv) : "memory");
          }
        }
      }
      asm volatile("s_waitcnt vmcnt(0)" ::: "memory");   // each thread drains its stores
      __syncthreads();                                    // block-wide: all stores in L3
      if (tid == 0)
        __hip_atomic_fetch_add(xready + by, 1, __ATOMIC_RELAXED, __HIP_MEMORY_SCOPE_AGENT);
      __syncthreads();
    }
    return;
  }

  // =================== scan role (R13, wave 0 only) ===================
  const int tid = threadIdx.x;
  if (tid >= 64) return;                   // no __syncthreads below this point
  const int b = blockIdx.x;
  const int jt = b >> 2, bt = b & 3;
  const int g = tid >> 4, l15 = tid & 15;
  const int j0 = jt * 16, b0 = bt * 16;

  bf16x8 wb[32], wo[32];
#pragma unroll
  for (int kk = 0; kk < 32; ++kk) {
    wb[kk] = *(const bf16x8*)(wh  + (size_t)(j0 + l15) * 1024 + kk * 32 + g * 8);
    wo[kk] = *(const bf16x8*)(w2o + (size_t)(j0 + l15) * 1024 + kk * 32 + g * 8);
  }
  const float4 bias_o = *(const float4*)(b_h2o + j0 + g * 4);

  const int* fl = flags + (bt * 64 + tid) * 16;   // 64B-padded flag lines
  int* myflag = flags + (bt * 64 + jt) * 16;
  const int pofs = (b0 + l15) * 1024 + j0 + g * 4;

  int xconf = -1;                          // highest by confirmed ready

  for (int t = 0; t <= 512; ++t) {
    const unsigned short* hsrc = hx + (size_t)(t & 3) * 65536 + (size_t)b0 * 1024;

    // gate (quad-confirmed, amortized) + prefetch xp via sc0sc1
    uint2 xpc;
    if (t < 512) {
      int byg = t >> 1;
      if (byg > xconf) {
        const int* xr = xready + (byg & ~3);
        i32x4 rv;
        do {
          asm volatile("global_load_dwordx4 %0, %1, off sc0 sc1\n\ts_waitcnt vmcnt(0)"
                       : "=v"(rv) : "v"(xr) : "memory");
        } while (rv[0] < 8 || rv[1] < 8 || rv[2] < 8 || rv[3] < 8);
        xconf = (byg & ~3) + 3;
      }
      const unsigned short* xp = xproj + (size_t)t * 65536 + pofs;
      asm volatile("global_load_dwordx2 %0, %1, off sc0 sc1"
                   : "=v"(xpc) : "v"(xp) : "memory");
    }

    // barrier: wait for all 64 producers of my bt group
    int v;
    do {
      asm volatile("global_load_dword %0, %1, off sc0 sc1\n\ts_waitcnt vmcnt(0)"
                   : "=v"(v) : "v"(fl) : "memory");
    } while (__any(v < t));

    // coherent h[t] loads: B-fragments (lane l15 = batch col, g = k-slice)
    i32x4 ha[32];
#pragma unroll
    for (int kk = 0; kk < 32; ++kk) {
      const unsigned short* p = hsrc + (size_t)l15 * 1024 + kk * 32 + g * 8;
      asm volatile("global_load_dwordx4 %0, %1, off sc0 sc1"
                   : "=v"(ha[kk]) : "v"(p) : "memory");
    }

    if (t < 512) {
      unsigned short* hdst = hx + (size_t)((t + 1) & 3) * 65536;
      f32x4 acc[4];
#pragma unroll
      for (int i = 0; i < 4; ++i) acc[i] = (f32x4){0.f, 0.f, 0.f, 0.f};

      // pipelined consume: counted vmcnt + sched_barrier (rule 18)
      // NOTE: xp load (1 outstanding) counted in: +1 on each N.
#define MFMA_GROUP(base, n)                                                     \
      asm volatile("s_waitcnt vmcnt(" #n ")" ::: "memory");                     \
      __builtin_amdgcn_sched_barrier(0);                                        \
      _Pragma("unroll")                                                         \
      for (int kk = base; kk < base + 8; ++kk)                                  \
        acc[kk & 3] = __builtin_amdgcn_mfma_f32_16x16x32_bf16(                  \
            wb[kk], __builtin_bit_cast(bf16x8, ha[kk]), acc[kk & 3], 0, 0, 0);

      MFMA_GROUP(0, 24)
      MFMA_GROUP(8, 16)
      MFMA_GROUP(16, 8)
      MFMA_GROUP(24, 0)
#undef MFMA_GROUP

      f32x4 s = (acc[0] + acc[1]) + (acc[2] + acc[3]);

      // h_next[b0+l15][j0+g*4 .. +3] = tanh(s + xp): ONE dwordx2 store (no wait)
      {
        float z0 = s[0] + bf2f((unsigned short)(xpc.x & 0xFFFF));
        float z1 = s[1] + bf2f((unsigned short)(xpc.x >> 16));
        float z2 = s[2] + bf2f((unsigned short)(xpc.y & 0xFFFF));
        float z3 = s[3] + bf2f((unsigned short)(xpc.y >> 16));
        unsigned int v01 = (unsigned int)f2bf(fast_tanh(z0)) |
                           ((unsigned int)f2bf(fast_tanh(z1)) << 16);
        unsigned int v23 = (unsigned int)f2bf(fast_tanh(z2)) |
                           ((unsigned int)f2bf(fast_tanh(z3)) << 16);
        uint2 dvec = {v01, v23};
        unsigned short* p = hdst + pofs;
        asm volatile("global_store_dwordx2 %0, %1, off sc0 sc1"
                     :: "v"(p), "v"(dvec) : "memory");
      }

      // ---- y-MFMAs (register-only) run while the h-store ack drains ----
      f32x4 ay[4];
#pragma unroll
      for (int i = 0; i < 4; ++i) ay[i] = (f32x4){0.f, 0.f, 0.f, 0.f};
      if (t > 0) {
#pragma unroll
        for (int kk = 0; kk < 32; ++kk)
          ay[kk & 3] = __builtin_amdgcn_mfma_f32_16x16x32_bf16(
              wo[kk], __builtin_bit_cast(bf16x8, ha[kk]), ay[kk & 3], 0, 0, 0);
      }
      __builtin_amdgcn_sched_barrier(0);

      // h store ack completed under the y-MFMAs: publish is ~free now
      asm volatile("s_waitcnt vmcnt(0)" ::: "memory");
      if (tid == 0) {
        int tv = t + 1;
        asm volatile("global_store_dword %0, %1, off sc0 sc1"
                     :: "v"(myflag), "v"(tv) : "memory");
      }

      // y epilogue (off the critical path)
      if (t > 0) {
        f32x4 sy = (ay[0] + ay[1]) + (ay[2] + ay[3]);
        sy[0] += bias_o.x; sy[1] += bias_o.y; sy[2] += bias_o.z; sy[3] += bias_o.w;
        *(f32x4*)(y + (size_t)(t - 1) * 65536 + pofs) = sy;
      }
    } else {
      // drain iteration: ensure h[512] fragments landed, then emit y[511]
      asm volatile("s_waitcnt vmcnt(0)" ::: "memory");
      __builtin_amdgcn_sched_barrier(0);
      f32x4 ay[4];
#pragma unroll
      for (int i = 0; i < 4; ++i) ay[i] = (f32x4){0.f, 0.f, 0.f, 0.f};
#pragma unroll
      for (int kk = 0; kk < 32; ++kk)
        ay[kk & 3] = __builtin_amdgcn_mfma_f32_16x16x32_bf16(
            wo[kk], __builtin_bit_cast(bf16x8, ha[kk]), ay[kk & 3], 0, 0, 0);
      f32x4 sy = (ay[0] + ay[1]) + (ay[2] + ay[3]);
      sy[0] += bias_o.x; sy[1] += bias_o.y; sy[2] += bias_o.z; sy[3] += bias_o.w;
      *(f32x4*)(y + (size_t)(t - 1) * 65536 + pofs) = sy;
    }
  }
}

// ---------- launch ----------
extern "C" void kernel_launch(void* const* d_in, const int* in_sizes, int n_in,
                              void* d_out, int out_size, void* d_ws, size_t ws_size,
                              hipStream_t stream) {
  const float* x     = (const float*)d_in[0];   // (512,64,1024)
  const float* h0    = (const float*)d_in[1];   // (64,1024)
  const float* w_i2h = (const float*)d_in[2];   // (1024,2048)
  const float* b_i2h = (const float*)d_in[3];   // (1024)
  const float* w_h2o = (const float*)d_in[4];   // (1024,1024)
  const float* b_h2o = (const float*)d_in[5];   // (1024)

  // workspace: xproj bf16 (67,108,864) | hx 4 slices (524,288)
  //            | flags 16,384 + xready 1,024 | wx 2MB | wh 2MB | w2o 2MB
  char* ws = (char*)d_ws;
  unsigned short* xproj = (unsigned short*)ws;
  unsigned short* hx    = (unsigned short*)(ws + 67108864);
  int*            flags = (int*)(ws + 67108864 + 524288);
  int*            xready = flags + 4096;
  unsigned short* wx    = (unsigned short*)(ws + 67108864 + 524288 + 17408);
  unsigned short* wh    = wx + 1024 * 1024;
  unsigned short* w2o   = wh + 1024 * 1024;
  float* y = (float*)d_out;                      // (512,64,1024) fp32

  convert_kernel<<<3136, 256, 0, stream>>>(w_i2h, w_h2o, h0, wx, wh, w2o, hx, flags);

  // fused: 256 scan blocks + 256 worker blocks, all resident (2 blocks/CU)
  fused_kernel<<<TOTAL_BLOCKS, 256, 0, stream>>>(x, b_i2h, wx, wh, w2o, b_h2o,
                                                 xproj, y, hx, flags, xready);
}

// Round 18
// 1636.507 us; speedup vs baseline: 2.0421x; 2.0421x over previous
//
#include <hip/hip_runtime.h>
#include <math.h>

// ---------- types / helpers ----------
typedef __attribute__((ext_vector_type(8))) short bf16x8;   // 8 bf16 = 4 VGPR
typedef __attribute__((ext_vector_type(4))) int   i32x4;
typedef __attribute__((ext_vector_type(4))) float f32x4;    // MFMA acc
typedef __attribute__((ext_vector_type(4))) unsigned short u16x4;

__device__ __forceinline__ unsigned short f2bf(float x) {   // round-to-nearest-even
  unsigned int u = __builtin_bit_cast(unsigned int, x);
  return (unsigned short)((u + 0x7fffu + ((u >> 16) & 1u)) >> 16);
}
__device__ __forceinline__ float bf2f(unsigned short h) {
  unsigned int u = ((unsigned int)h) << 16;
  return __builtin_bit_cast(float, u);
}
// tanh via hw exp2: tanh(z) = 1 - 2/(e^{2z}+1)
__device__ __forceinline__ float fast_tanh(float z) {
  float e;
  asm("v_exp_f32 %0, %1" : "=v"(e) : "v"(z * 2.8853900817779268f));
  return 1.0f - 2.0f * __builtin_amdgcn_rcpf(e + 1.0f);
}

// ---------- K0: convert weights + h0 to bf16; zero barrier flags ----------
__global__ void convert_kernel(const float* __restrict__ w_i2h,
                               const float* __restrict__ w_h2o,
                               const float* __restrict__ h0,
                               unsigned short* __restrict__ wx,
                               unsigned short* __restrict__ wh,
                               unsigned short* __restrict__ w2o,
                               unsigned short* __restrict__ hx,
                               int* __restrict__ flags) {
  int idx = blockIdx.x * 256 + threadIdx.x;
  if (idx < 4096) flags[idx] = 0;          // padded flags (256 x 64B lines)
  int e = idx * 4;
  const float* src;
  unsigned short* dst;
  if (e < 2097152) {                       // w_i2h
    int row = e >> 11, col = e & 2047;
    src = w_i2h + e;
    dst = (col < 1024) ? (wx + row * 1024 + col) : (wh + row * 1024 + (col - 1024));
  } else if (e < 3145728) {                // w_h2o
    int i = e - 2097152; src = w_h2o + i; dst = w2o + i;
  } else {                                 // h0 -> hx slice 0
    int i = e - 3145728; src = h0 + i; dst = hx + i;
  }
  float4 v = *(const float4*)src;
  u16x4 o = {f2bf(v.x), f2bf(v.y), f2bf(v.z), f2bf(v.w)};
  *(u16x4*)dst = o;
}

// ---------- GEMM: C[M,N] = A[M,K] * B[N,K]^T + bias[N] ----------
// 128x128 tile, BK=64, 4 waves (2x2 of 64x64), 16x16x32 bf16 MFMA.
template <bool AF32, bool OUTBF16>
__global__ __launch_bounds__(256) void gemm_bt(const void* __restrict__ Ap,
                                               const unsigned short* __restrict__ B,
                                               const float* __restrict__ bias,
                                               void* __restrict__ Cp,
                                               int M, int N, int K) {
  __shared__ __attribute__((aligned(16))) unsigned short lA[128 * 64];
  __shared__ __attribute__((aligned(16))) unsigned short lB[128 * 64];
  const int tid = threadIdx.x;
  const int bx = blockIdx.x & 7;       // N/128 == 8
  const int by = blockIdx.x >> 3;
  const int lane = tid & 63, w = tid >> 6;
  const int g = lane >> 4, l15 = lane & 15;
  const int wm = w >> 1, wn = w & 1;

  f32x4 acc[4][4];
#pragma unroll
  for (int i = 0; i < 4; ++i)
#pragma unroll
    for (int j = 0; j < 4; ++j) acc[i][j] = (f32x4){0.f, 0.f, 0.f, 0.f};

  const int nK = K >> 6;
  for (int kt = 0; kt < nK; ++kt) {
    const int k0 = kt << 6;
#pragma unroll
    for (int i = 0; i < 4; ++i) {
      int cl = i * 256 + tid;
      int row = cl >> 3, cc = cl & 7;
      bf16x8 av;
      if (AF32) {
        const float* ap = (const float*)Ap + (size_t)(by * 128 + row) * K + k0 + cc * 8;
        float4 f0 = *(const float4*)ap;
        float4 f1 = *(const float4*)(ap + 4);
        av = (bf16x8){(short)f2bf(f0.x), (short)f2bf(f0.y), (short)f2bf(f0.z), (short)f2bf(f0.w),
                      (short)f2bf(f1.x), (short)f2bf(f1.y), (short)f2bf(f1.z), (short)f2bf(f1.w)};
      } else {
        const unsigned short* ap = (const unsigned short*)Ap + (size_t)(by * 128 + row) * K + k0 + cc * 8;
        av = *(const bf16x8*)ap;
      }
      *(bf16x8*)&lA[(row * 8 + (cc ^ (row & 7))) * 8] = av;
      const unsigned short* bp = B + (size_t)(bx * 128 + row) * K + k0 + cc * 8;
      bf16x8 bv = *(const bf16x8*)bp;
      *(bf16x8*)&lB[(row * 8 + (cc ^ (row & 7))) * 8] = bv;
    }
    __syncthreads();
#pragma unroll
    for (int kk = 0; kk < 2; ++kk) {
      bf16x8 av[4], bv[4];
#pragma unroll
      for (int mt = 0; mt < 4; ++mt) {
        int r = wm * 64 + mt * 16 + l15;
        av[mt] = *(const bf16x8*)&lA[(r * 8 + ((kk * 4 + g) ^ (r & 7))) * 8];
      }
#pragma unroll
      for (int nt = 0; nt < 4; ++nt) {
        int r = wn * 64 + nt * 16 + l15;
        bv[nt] = *(const bf16x8*)&lB[(r * 8 + ((kk * 4 + g) ^ (r & 7))) * 8];
      }
#pragma unroll
      for (int mt = 0; mt < 4; ++mt)
#pragma unroll
        for (int nt = 0; nt < 4; ++nt)
          acc[mt][nt] = __builtin_amdgcn_mfma_f32_16x16x32_bf16(av[mt], bv[nt], acc[mt][nt], 0, 0, 0);
    }
    __syncthreads();
  }
#pragma unroll
  for (int mt = 0; mt < 4; ++mt) {
    int grow = by * 128 + wm * 64 + mt * 16 + g * 4;
#pragma unroll
    for (int nt = 0; nt < 4; ++nt) {
      int col = bx * 128 + wn * 64 + nt * 16 + l15;
      float bs = bias[col];
#pragma unroll
      for (int r = 0; r < 4; ++r) {
        size_t off = (size_t)(grow + r) * N + col;
        float v = acc[mt][nt][r] + bs;
        if (OUTBF16) ((unsigned short*)Cp)[off] = f2bf(v);
        else ((float*)Cp)[off] = v;
      }
    }
  }
}

// ---------- K2: persistent scan + fused y-GEMM, split-phase detect ----------
// R13 structure (256 blocks x 1 wave; block (jt,bt): 16 j/o-cols x 16 batches;
// operand-swapped MFMA; padded flags; 4-slice hx ring; y[t-1] from ha=h[t]
// shadowed under the h-store drain). Change vs R13: the detect is split —
// chunk kk depends only on producer 2kk+(g>>1), so once producers 0..31 are
// ready (lower 32 lanes' flags) the kk=0..15 h-loads are issued and complete
// IN PARALLEL with the phase-2 poll for producers 32..63 (each poll round's
// vmcnt(0) drains them). MFMA group waits: first half in-regs, second half
// counted 16/8/0.
#define SCAN_BLOCKS 256
__global__ __launch_bounds__(64, 1) void rnn_scan(const unsigned short* __restrict__ xproj,
                                                  const unsigned short* __restrict__ wh,
                                                  const unsigned short* __restrict__ w2o,
                                                  const float* __restrict__ b_h2o,
                                                  float* __restrict__ y,
                                                  unsigned short* __restrict__ hx,
                                                  int* __restrict__ flags) {
  const int tid = threadIdx.x;          // 0..63
  const int b = blockIdx.x;
  const int jt = b >> 2, bt = b & 3;
  const int g = tid >> 4, l15 = tid & 15;
  const int j0 = jt * 16, b0 = bt * 16;

  // resident fragments: wh / w2o rows j0..j0+15 (lane l15 = row, g = k-slice)
  bf16x8 wb[32], wo[32];
#pragma unroll
  for (int kk = 0; kk < 32; ++kk) {
    wb[kk] = *(const bf16x8*)(wh  + (size_t)(j0 + l15) * 1024 + kk * 32 + g * 8);
    wo[kk] = *(const bf16x8*)(w2o + (size_t)(j0 + l15) * 1024 + kk * 32 + g * 8);
  }
  const float4 bias_o = *(const float4*)(b_h2o + j0 + g * 4);

  const int* fl = flags + (bt * 64 + tid) * 16;   // lane tid polls producer tid
  int* myflag = flags + (bt * 64 + jt) * 16;
  const int pofs = (b0 + l15) * 1024 + j0 + g * 4;

  for (int t = 0; t <= 512; ++t) {
    const unsigned short* hsrc = hx + (size_t)(t & 3) * 65536 + (size_t)b0 * 1024;

    // prefetch xp (plain cached; drained by the first poll round)
    uint2 xpc;
    if (t < 512)
      xpc = *(const uint2*)(xproj + (size_t)t * 65536 + pofs);

    i32x4 ha[32];
    int v;
    // --- phase 1: wait for producers 0..31 (lower 32 lanes' flags) ---
    do {
      asm volatile("global_load_dword %0, %1, off sc0 sc1\n\ts_waitcnt vmcnt(0)"
                   : "=v"(v) : "v"(fl) : "memory");
    } while (__ballot(v < t) & 0xFFFFFFFFull);
    // issue first-half h-loads (chunks kk<16 depend only on producers 0..31)
#pragma unroll
    for (int kk = 0; kk < 16; ++kk) {
      const unsigned short* p = hsrc + (size_t)l15 * 1024 + kk * 32 + g * 8;
      asm volatile("global_load_dwordx4 %0, %1, off sc0 sc1"
                   : "=v"(ha[kk]) : "v"(p) : "memory");
    }
    // --- phase 2: wait for all producers (first-half loads drain underneath) ---
    do {
      asm volatile("global_load_dword %0, %1, off sc0 sc1\n\ts_waitcnt vmcnt(0)"
                   : "=v"(v) : "v"(fl) : "memory");
    } while (__ballot(v < t));
    // issue second-half h-loads (16 outstanding after this)
#pragma unroll
    for (int kk = 16; kk < 32; ++kk) {
      const unsigned short* p = hsrc + (size_t)l15 * 1024 + kk * 32 + g * 8;
      asm volatile("global_load_dwordx4 %0, %1, off sc0 sc1"
                   : "=v"(ha[kk]) : "v"(p) : "memory");
    }

    if (t < 512) {
      unsigned short* hdst = hx + (size_t)((t + 1) & 3) * 65536;
      f32x4 acc[4];
#pragma unroll
      for (int i = 0; i < 4; ++i) acc[i] = (f32x4){0.f, 0.f, 0.f, 0.f};

      // pipelined consume (rule 18): first half already in regs; second half
      // counted against the 16 outstanding loads.
#define MFMA_GROUP(base, n)                                                     \
      asm volatile("s_waitcnt vmcnt(" #n ")" ::: "memory");                     \
      __builtin_amdgcn_sched_barrier(0);                                        \
      _Pragma("unroll")                                                         \
      for (int kk = base; kk < base + 8; ++kk)                                  \
        acc[kk & 3] = __builtin_amdgcn_mfma_f32_16x16x32_bf16(                  \
            wb[kk], __builtin_bit_cast(bf16x8, ha[kk]), acc[kk & 3], 0, 0, 0);

      MFMA_GROUP(0, 16)
      MFMA_GROUP(8, 16)
      MFMA_GROUP(16, 8)
      MFMA_GROUP(24, 0)
#undef MFMA_GROUP

      f32x4 s = (acc[0] + acc[1]) + (acc[2] + acc[3]);

      // h_next[b0+l15][j0+g*4 .. +3] = tanh(s + xp): ONE dwordx2 store (no wait)
      {
        float z0 = s[0] + bf2f((unsigned short)(xpc.x & 0xFFFF));
        float z1 = s[1] + bf2f((unsigned short)(xpc.x >> 16));
        float z2 = s[2] + bf2f((unsigned short)(xpc.y & 0xFFFF));
        float z3 = s[3] + bf2f((unsigned short)(xpc.y >> 16));
        unsigned int v01 = (unsigned int)f2bf(fast_tanh(z0)) |
                           ((unsigned int)f2bf(fast_tanh(z1)) << 16);
        unsigned int v23 = (unsigned int)f2bf(fast_tanh(z2)) |
                           ((unsigned int)f2bf(fast_tanh(z3)) << 16);
        uint2 dvec = {v01, v23};
        unsigned short* p = hdst + pofs;
        asm volatile("global_store_dwordx2 %0, %1, off sc0 sc1"
                     :: "v"(p), "v"(dvec) : "memory");
      }

      // ---- y-MFMAs (register-only) run while the h-store ack drains ----
      f32x4 ay[4];
#pragma unroll
      for (int i = 0; i < 4; ++i) ay[i] = (f32x4){0.f, 0.f, 0.f, 0.f};
      if (t > 0) {
#pragma unroll
        for (int kk = 0; kk < 32; ++kk)
          ay[kk & 3] = __builtin_amdgcn_mfma_f32_16x16x32_bf16(
              wo[kk], __builtin_bit_cast(bf16x8, ha[kk]), ay[kk & 3], 0, 0, 0);
      }
      __builtin_amdgcn_sched_barrier(0);

      // h store ack completed under the y-MFMAs: publish is ~free now
      asm volatile("s_waitcnt vmcnt(0)" ::: "memory");
      if (tid == 0) {
        int tv = t + 1;
        asm volatile("global_store_dword %0, %1, off sc0 sc1"
                     :: "v"(myflag), "v"(tv) : "memory");
      }

      // y epilogue (off the critical path)
      if (t > 0) {
        f32x4 sy = (ay[0] + ay[1]) + (ay[2] + ay[3]);
        sy[0] += bias_o.x; sy[1] += bias_o.y; sy[2] += bias_o.z; sy[3] += bias_o.w;
        *(f32x4*)(y + (size_t)(t - 1) * 65536 + pofs) = sy;
      }
    } else {
      // drain iteration: ensure h[512] fragments landed, then emit y[511]
      asm volatile("s_waitcnt vmcnt(0)" ::: "memory");
      __builtin_amdgcn_sched_barrier(0);
      f32x4 ay[4];
#pragma unroll
      for (int i = 0; i < 4; ++i) ay[i] = (f32x4){0.f, 0.f, 0.f, 0.f};
#pragma unroll
      for (int kk = 0; kk < 32; ++kk)
        ay[kk & 3] = __builtin_amdgcn_mfma_f32_16x16x32_bf16(
            wo[kk], __builtin_bit_cast(bf16x8, ha[kk]), ay[kk & 3], 0, 0, 0);
      f32x4 sy = (ay[0] + ay[1]) + (ay[2] + ay[3]);
      sy[0] += bias_o.x; sy[1] += bias_o.y; sy[2] += bias_o.z; sy[3] += bias_o.w;
      *(f32x4*)(y + (size_t)(t - 1) * 65536 + pofs) = sy;
    }
  }
}

// ---------- launch ----------
extern "C" void kernel_launch(void* const* d_in, const int* in_sizes, int n_in,
                              void* d_out, int out_size, void* d_ws, size_t ws_size,
                              hipStream_t stream) {
  const float* x     = (const float*)d_in[0];   // (512,64,1024)
  const float* h0    = (const float*)d_in[1];   // (64,1024)
  const float* w_i2h = (const float*)d_in[2];   // (1024,2048)
  const float* b_i2h = (const float*)d_in[3];   // (1024)
  const float* w_h2o = (const float*)d_in[4];   // (1024,1024)
  const float* b_h2o = (const float*)d_in[5];   // (1024)

  // workspace: xproj bf16 (67,108,864) | hx 4 slices (524,288) | flags (16,384)
  //            | wx 2MB | wh 2MB | w2o 2MB   (~73.9 MB)
  char* ws = (char*)d_ws;
  unsigned short* xproj = (unsigned short*)ws;
  unsigned short* hx    = (unsigned short*)(ws + 67108864);
  int*            flags = (int*)(ws + 67108864 + 524288);
  unsigned short* wx    = (unsigned short*)(ws + 67108864 + 524288 + 16384);
  unsigned short* wh    = wx + 1024 * 1024;
  unsigned short* w2o   = wh + 1024 * 1024;
  float* y = (float*)d_out;                      // (512,64,1024) fp32

  convert_kernel<<<3136, 256, 0, stream>>>(w_i2h, w_h2o, h0, wx, wh, w2o, hx, flags);

  // xproj = x @ wx^T + b_i2h   (M=32768, N=1024, K=1024) -> ws
  gemm_bt<true, true><<<2048, 256, 0, stream>>>((const void*)x, wx, b_i2h,
                                                (void*)xproj, 32768, 1024, 1024);

  // persistent 512-step recurrence, split-phase detect, fused y-GEMM -> d_out
  rnn_scan<<<SCAN_BLOCKS, 64, 0, stream>>>(xproj, wh, w2o, b_h2o, y, hx, flags);
}

// Round 19
// 1478.481 us; speedup vs baseline: 2.2604x; 1.1069x over previous
//
#include <hip/hip_runtime.h>
#include <math.h>

// ---------- types / helpers ----------
typedef __attribute__((ext_vector_type(8))) short bf16x8;   // 8 bf16 = 4 VGPR
typedef __attribute__((ext_vector_type(4))) int   i32x4;
typedef __attribute__((ext_vector_type(4))) float f32x4;    // MFMA acc
typedef __attribute__((ext_vector_type(4))) unsigned short u16x4;

__device__ __forceinline__ unsigned short f2bf(float x) {   // round-to-nearest-even
  unsigned int u = __builtin_bit_cast(unsigned int, x);
  return (unsigned short)((u + 0x7fffu + ((u >> 16) & 1u)) >> 16);
}
__device__ __forceinline__ float bf2f(unsigned short h) {
  unsigned int u = ((unsigned int)h) << 16;
  return __builtin_bit_cast(float, u);
}
// tanh via hw exp2: tanh(z) = 1 - 2/(e^{2z}+1)
__device__ __forceinline__ float fast_tanh(float z) {
  float e;
  asm("v_exp_f32 %0, %1" : "=v"(e) : "v"(z * 2.8853900817779268f));
  return 1.0f - 2.0f * __builtin_amdgcn_rcpf(e + 1.0f);
}

// ---------- K0: convert weights + h0 to bf16; zero barrier flags ----------
__global__ void convert_kernel(const float* __restrict__ w_i2h,
                               const float* __restrict__ w_h2o,
                               const float* __restrict__ h0,
                               unsigned short* __restrict__ wx,
                               unsigned short* __restrict__ wh,
                               unsigned short* __restrict__ w2o,
                               unsigned short* __restrict__ hx,
                               int* __restrict__ flags) {
  int idx = blockIdx.x * 256 + threadIdx.x;
  if (idx < 4096) flags[idx] = 0;          // padded flags (256 x 64B lines)
  int e = idx * 4;
  const float* src;
  unsigned short* dst;
  if (e < 2097152) {                       // w_i2h
    int row = e >> 11, col = e & 2047;
    src = w_i2h + e;
    dst = (col < 1024) ? (wx + row * 1024 + col) : (wh + row * 1024 + (col - 1024));
  } else if (e < 3145728) {                // w_h2o
    int i = e - 2097152; src = w_h2o + i; dst = w2o + i;
  } else {                                 // h0 -> hx slice 0
    int i = e - 3145728; src = h0 + i; dst = hx + i;
  }
  float4 v = *(const float4*)src;
  u16x4 o = {f2bf(v.x), f2bf(v.y), f2bf(v.z), f2bf(v.w)};
  *(u16x4*)dst = o;
}

// ---------- GEMM: C[M,N] = A[M,K] * B[N,K]^T + bias[N] ----------
// 128x128 tile, BK=64, 4 waves (2x2 of 64x64), 16x16x32 bf16 MFMA.
template <bool AF32, bool OUTBF16>
__global__ __launch_bounds__(256) void gemm_bt(const void* __restrict__ Ap,
                                               const unsigned short* __restrict__ B,
                                               const float* __restrict__ bias,
                                               void* __restrict__ Cp,
                                               int M, int N, int K) {
  __shared__ __attribute__((aligned(16))) unsigned short lA[128 * 64];
  __shared__ __attribute__((aligned(16))) unsigned short lB[128 * 64];
  const int tid = threadIdx.x;
  const int bx = blockIdx.x & 7;       // N/128 == 8
  const int by = blockIdx.x >> 3;
  const int lane = tid & 63, w = tid >> 6;
  const int g = lane >> 4, l15 = lane & 15;
  const int wm = w >> 1, wn = w & 1;

  f32x4 acc[4][4];
#pragma unroll
  for (int i = 0; i < 4; ++i)
#pragma unroll
    for (int j = 0; j < 4; ++j) acc[i][j] = (f32x4){0.f, 0.f, 0.f, 0.f};

  const int nK = K >> 6;
  for (int kt = 0; kt < nK; ++kt) {
    const int k0 = kt << 6;
#pragma unroll
    for (int i = 0; i < 4; ++i) {
      int cl = i * 256 + tid;
      int row = cl >> 3, cc = cl & 7;
      bf16x8 av;
      if (AF32) {
        const float* ap = (const float*)Ap + (size_t)(by * 128 + row) * K + k0 + cc * 8;
        float4 f0 = *(const float4*)ap;
        float4 f1 = *(const float4*)(ap + 4);
        av = (bf16x8){(short)f2bf(f0.x), (short)f2bf(f0.y), (short)f2bf(f0.z), (short)f2bf(f0.w),
                      (short)f2bf(f1.x), (short)f2bf(f1.y), (short)f2bf(f1.z), (short)f2bf(f1.w)};
      } else {
        const unsigned short* ap = (const unsigned short*)Ap + (size_t)(by * 128 + row) * K + k0 + cc * 8;
        av = *(const bf16x8*)ap;
      }
      *(bf16x8*)&lA[(row * 8 + (cc ^ (row & 7))) * 8] = av;
      const unsigned short* bp = B + (size_t)(bx * 128 + row) * K + k0 + cc * 8;
      bf16x8 bv = *(const bf16x8*)bp;
      *(bf16x8*)&lB[(row * 8 + (cc ^ (row & 7))) * 8] = bv;
    }
    __syncthreads();
#pragma unroll
    for (int kk = 0; kk < 2; ++kk) {
      bf16x8 av[4], bv[4];
#pragma unroll
      for (int mt = 0; mt < 4; ++mt) {
        int r = wm * 64 + mt * 16 + l15;
        av[mt] = *(const bf16x8*)&lA[(r * 8 + ((kk * 4 + g) ^ (r & 7))) * 8];
      }
#pragma unroll
      for (int nt = 0; nt < 4; ++nt) {
        int r = wn * 64 + nt * 16 + l15;
        bv[nt] = *(const bf16x8*)&lB[(r * 8 + ((kk * 4 + g) ^ (r & 7))) * 8];
      }
#pragma unroll
      for (int mt = 0; mt < 4; ++mt)
#pragma unroll
        for (int nt = 0; nt < 4; ++nt)
          acc[mt][nt] = __builtin_amdgcn_mfma_f32_16x16x32_bf16(av[mt], bv[nt], acc[mt][nt], 0, 0, 0);
    }
    __syncthreads();
  }
#pragma unroll
  for (int mt = 0; mt < 4; ++mt) {
    int grow = by * 128 + wm * 64 + mt * 16 + g * 4;
#pragma unroll
    for (int nt = 0; nt < 4; ++nt) {
      int col = bx * 128 + wn * 64 + nt * 16 + l15;
      float bs = bias[col];
#pragma unroll
      for (int r = 0; r < 4; ++r) {
        size_t off = (size_t)(grow + r) * N + col;
        float v = acc[mt][nt][r] + bs;
        if (OUTBF16) ((unsigned short*)Cp)[off] = f2bf(v);
        else ((float*)Cp)[off] = v;
      }
    }
  }
}

// ---------- K2: persistent scan + fused y-GEMM, drain-shadowed publish ----------
// Best verified structure (R13): 256 blocks x 1 wave; block (jt,bt) owns 16
// j/o-cols x 16 batches; per-bt-group 64-flag barrier (64B-padded lines);
// sc0sc1 L3 exchange; 4-slice hx ring; operand-swapped MFMA (lane outputs 4
// j-consecutive values); y[t-1] computed from ha=h[t] with the y-MFMAs placed
// between the h-store and the vmcnt(0)+flag-publish so the store's L3 ack
// drains underneath them.
#define SCAN_BLOCKS 256
__global__ __launch_bounds__(64, 1) void rnn_scan(const unsigned short* __restrict__ xproj,
                                                  const unsigned short* __restrict__ wh,
                                                  const unsigned short* __restrict__ w2o,
                                                  const float* __restrict__ b_h2o,
                                                  float* __restrict__ y,
                                                  unsigned short* __restrict__ hx,
                                                  int* __restrict__ flags) {
  const int tid = threadIdx.x;          // 0..63
  const int b = blockIdx.x;
  const int jt = b >> 2, bt = b & 3;
  const int g = tid >> 4, l15 = tid & 15;
  const int j0 = jt * 16, b0 = bt * 16;

  // resident fragments: wh / w2o rows j0..j0+15 (lane l15 = row, g = k-slice)
  bf16x8 wb[32], wo[32];
#pragma unroll
  for (int kk = 0; kk < 32; ++kk) {
    wb[kk] = *(const bf16x8*)(wh  + (size_t)(j0 + l15) * 1024 + kk * 32 + g * 8);
    wo[kk] = *(const bf16x8*)(w2o + (size_t)(j0 + l15) * 1024 + kk * 32 + g * 8);
  }
  // after swap each lane outputs j = j0+g*4 .. +3 -> float4 bias
  const float4 bias_o = *(const float4*)(b_h2o + j0 + g * 4);

  const int* fl = flags + (bt * 64 + tid) * 16;   // 64B-padded flag lines
  int* myflag = flags + (bt * 64 + jt) * 16;

  // per-lane element offset for h-store / xp / y (batch b0+l15, j j0+g*4)
  const int pofs = (b0 + l15) * 1024 + j0 + g * 4;

  for (int t = 0; t <= 512; ++t) {
    const unsigned short* hsrc = hx + (size_t)(t & 3) * 65536 + (size_t)b0 * 1024;

    // prefetch xp for the recurrence (skip on the drain iteration)
    uint2 xpc;
    if (t < 512)
      xpc = *(const uint2*)(xproj + (size_t)t * 65536 + pofs);

    // barrier: wait for all 64 producers of my bt group (one coherent load/lane)
    int v;
    do {
      asm volatile("global_load_dword %0, %1, off sc0 sc1\n\ts_waitcnt vmcnt(0)"
                   : "=v"(v) : "v"(fl) : "memory");
    } while (__any(v < t));

    // coherent h[t] loads: B-fragments (lane l15 = batch col, g = k-slice)
    i32x4 ha[32];
#pragma unroll
    for (int kk = 0; kk < 32; ++kk) {
      const unsigned short* p = hsrc + (size_t)l15 * 1024 + kk * 32 + g * 8;
      asm volatile("global_load_dwordx4 %0, %1, off sc0 sc1"
                   : "=v"(ha[kk]) : "v"(p) : "memory");
    }

    if (t < 512) {
      unsigned short* hdst = hx + (size_t)((t + 1) & 3) * 65536;
      f32x4 acc[4];
#pragma unroll
      for (int i = 0; i < 4; ++i) acc[i] = (f32x4){0.f, 0.f, 0.f, 0.f};

      // pipelined consume: counted vmcnt + sched_barrier (rule 18)
      // D[r=j][c=batch] = sum_k wh[j0+r][k] * h[b0+c][k]
#define MFMA_GROUP(base, n)                                                     \
      asm volatile("s_waitcnt vmcnt(" #n ")" ::: "memory");                     \
      __builtin_amdgcn_sched_barrier(0);                                        \
      _Pragma("unroll")                                                         \
      for (int kk = base; kk < base + 8; ++kk)                                  \
        acc[kk & 3] = __builtin_amdgcn_mfma_f32_16x16x32_bf16(                  \
            wb[kk], __builtin_bit_cast(bf16x8, ha[kk]), acc[kk & 3], 0, 0, 0);

      MFMA_GROUP(0, 24)
      MFMA_GROUP(8, 16)
      MFMA_GROUP(16, 8)
      MFMA_GROUP(24, 0)
#undef MFMA_GROUP

      f32x4 s = (acc[0] + acc[1]) + (acc[2] + acc[3]);

      // h_next[b0+l15][j0+g*4 .. +3] = tanh(s + xp): ONE dwordx2 store (no wait)
      {
        float z0 = s[0] + bf2f((unsigned short)(xpc.x & 0xFFFF));
        float z1 = s[1] + bf2f((unsigned short)(xpc.x >> 16));
        float z2 = s[2] + bf2f((unsigned short)(xpc.y & 0xFFFF));
        float z3 = s[3] + bf2f((unsigned short)(xpc.y >> 16));
        unsigned int v01 = (unsigned int)f2bf(fast_tanh(z0)) |
                           ((unsigned int)f2bf(fast_tanh(z1)) << 16);
        unsigned int v23 = (unsigned int)f2bf(fast_tanh(z2)) |
                           ((unsigned int)f2bf(fast_tanh(z3)) << 16);
        uint2 dvec = {v01, v23};
        unsigned short* p = hdst + pofs;
        asm volatile("global_store_dwordx2 %0, %1, off sc0 sc1"
                     :: "v"(p), "v"(dvec) : "memory");
      }

      // ---- y-MFMAs (register-only) run while the h-store ack drains ----
      f32x4 ay[4];
#pragma unroll
      for (int i = 0; i < 4; ++i) ay[i] = (f32x4){0.f, 0.f, 0.f, 0.f};
      if (t > 0) {
#pragma unroll
        for (int kk = 0; kk < 32; ++kk)
          ay[kk & 3] = __builtin_amdgcn_mfma_f32_16x16x32_bf16(
              wo[kk], __builtin_bit_cast(bf16x8, ha[kk]), ay[kk & 3], 0, 0, 0);
      }
      __builtin_amdgcn_sched_barrier(0);

      // h store ack has completed under the y-MFMAs: publish is ~free now
      asm volatile("s_waitcnt vmcnt(0)" ::: "memory");
      if (tid == 0) {
        int tv = t + 1;
        asm volatile("global_store_dword %0, %1, off sc0 sc1"
                     :: "v"(myflag), "v"(tv) : "memory");
      }

      // y epilogue (off the critical path)
      if (t > 0) {
        f32x4 sy = (ay[0] + ay[1]) + (ay[2] + ay[3]);
        sy[0] += bias_o.x; sy[1] += bias_o.y; sy[2] += bias_o.z; sy[3] += bias_o.w;
        *(f32x4*)(y + (size_t)(t - 1) * 65536 + pofs) = sy;
      }
    } else {
      // drain iteration: ensure h[512] fragments landed, then emit y[511]
      asm volatile("s_waitcnt vmcnt(0)" ::: "memory");
      __builtin_amdgcn_sched_barrier(0);
      f32x4 ay[4];
#pragma unroll
      for (int i = 0; i < 4; ++i) ay[i] = (f32x4){0.f, 0.f, 0.f, 0.f};
#pragma unroll
      for (int kk = 0; kk < 32; ++kk)
        ay[kk & 3] = __builtin_amdgcn_mfma_f32_16x16x32_bf16(
            wo[kk], __builtin_bit_cast(bf16x8, ha[kk]), ay[kk & 3], 0, 0, 0);
      f32x4 sy = (ay[0] + ay[1]) + (ay[2] + ay[3]);
      sy[0] += bias_o.x; sy[1] += bias_o.y; sy[2] += bias_o.z; sy[3] += bias_o.w;
      *(f32x4*)(y + (size_t)(t - 1) * 65536 + pofs) = sy;
    }
  }
}

// ---------- launch ----------
extern "C" void kernel_launch(void* const* d_in, const int* in_sizes, int n_in,
                              void* d_out, int out_size, void* d_ws, size_t ws_size,
                              hipStream_t stream) {
  const float* x     = (const float*)d_in[0];   // (512,64,1024)
  const float* h0    = (const float*)d_in[1];   // (64,1024)
  const float* w_i2h = (const float*)d_in[2];   // (1024,2048)
  const float* b_i2h = (const float*)d_in[3];   // (1024)
  const float* w_h2o = (const float*)d_in[4];   // (1024,1024)
  const float* b_h2o = (const float*)d_in[5];   // (1024)

  // workspace: xproj bf16 (67,108,864) | hx 4 slices (524,288) | flags (16,384)
  //            | wx 2MB | wh 2MB | w2o 2MB   (~73.9 MB)
  char* ws = (char*)d_ws;
  unsigned short* xproj = (unsigned short*)ws;
  unsigned short* hx    = (unsigned short*)(ws + 67108864);
  int*            flags = (int*)(ws + 67108864 + 524288);
  unsigned short* wx    = (unsigned short*)(ws + 67108864 + 524288 + 16384);
  unsigned short* wh    = wx + 1024 * 1024;
  unsigned short* w2o   = wh + 1024 * 1024;
  float* y = (float*)d_out;                      // (512,64,1024) fp32

  convert_kernel<<<3136, 256, 0, stream>>>(w_i2h, w_h2o, h0, wx, wh, w2o, hx, flags);

  // xproj = x @ wx^T + b_i2h   (M=32768, N=1024, K=1024) -> ws
  gemm_bt<true, true><<<2048, 256, 0, stream>>>((const void*)x, wx, b_i2h,
                                                (void*)xproj, 32768, 1024, 1024);

  // persistent 512-step recurrence with fused (shifted) output GEMM -> d_out
  rnn_scan<<<SCAN_BLOCKS, 64, 0, stream>>>(xproj, wh, w2o, b_h2o, y, hx, flags);
}